// Round 18
// baseline (136.599 us; speedup 1.0000x reference)
//
#include <hip/hip_runtime.h>
#include <hip/hip_bf16.h>

// Fused: QKV proj (+bias) -> RoPE(Q,K) -> MHA softmax -> out proj (+bias)
// B=8 S=1024 D=1024 H=16 Dk=64.
// R18 = R17 geometry (wave 128x64, 256x128 tile, 768/256 blocks, XCD m-chunk)
// with mfma_f32_32x32x16_bf16: 16 MFMA/32k @ ~8cy vs 32 @ ~4.85cy (pipe time
// x0.83), half the MFMA+load issue slots, frag regs 96->48. Fragment granule:
// 32 rows x 16 k per (rg32,kt16), lane l -> row=l&31, k=(l>>5)*8+j. C/D map
// (verified m74/m101): col=l&31, row=(reg&3)+8*(reg>>2)+4*(l>>5).
// Attn compute byte-identical to R16/R17 (T13 defer-max); its epilogue now
// writes Ogf in 32-granule for out-proj.

typedef __bf16 bf16_t;
typedef __bf16 bf16x8 __attribute__((ext_vector_type(8)));
typedef float  f32x4  __attribute__((ext_vector_type(4)));
typedef float  f32x16 __attribute__((ext_vector_type(16)));

static __device__ __forceinline__ f32x4 mfma16(bf16x8 a, bf16x8 b, f32x4 c) {
  return __builtin_amdgcn_mfma_f32_16x16x32_bf16(a, b, c, 0, 0, 0);
}
static __device__ __forceinline__ f32x16 mfma32(bf16x8 a, bf16x8 b, f32x16 c) {
  return __builtin_amdgcn_mfma_f32_32x32x16_bf16(a, b, c, 0, 0, 0);
}

#if __has_builtin(__builtin_amdgcn_exp2f)
#define EXP2F(x) __builtin_amdgcn_exp2f(x)
#else
#define EXP2F(x) exp2f(x)
#endif

// ---------------- prep: 32-row fragment-granule casts + rope table --------
// Granule (rg32,kt16,lane) at elem off ((rg32*64+kt16)*64+lane)*8 holds
// M[rg32*32 + (lane&31)][kt16*16 + (lane>>5)*8 + j], j in [0,8).
__global__ void k_prep(const float* __restrict__ x, const float* __restrict__ Wq,
                       const float* __restrict__ Wk, const float* __restrict__ Wv,
                       const float* __restrict__ Wo, const int* __restrict__ pos,
                       bf16_t* __restrict__ Xf, bf16_t* __restrict__ Wf,
                       float2* __restrict__ rt) {
  const int bid = blockIdx.x;
  const int t = threadIdx.x;
  if (bid < 4096) {                     // x -> Xf (8192x1024, 1Mi granules)
    int g = bid * 256 + t;
    int rg = g >> 12, kt = (g >> 6) & 63, lane = g & 63;
    int m = rg * 32 + (lane & 31);
    int k = kt * 16 + (lane >> 5) * 8;
    const float* s = x + (size_t)m * 1024 + k;
    float4 v0 = *(const float4*)s;
    float4 v1 = *(const float4*)(s + 4);
    union { bf16_t b[8]; } pk;
    pk.b[0] = (bf16_t)v0.x; pk.b[1] = (bf16_t)v0.y; pk.b[2] = (bf16_t)v0.z; pk.b[3] = (bf16_t)v0.w;
    pk.b[4] = (bf16_t)v1.x; pk.b[5] = (bf16_t)v1.y; pk.b[6] = (bf16_t)v1.z; pk.b[7] = (bf16_t)v1.w;
    __builtin_memcpy(Xf + (size_t)g * 8, pk.b, 16);
  } else if (bid < 6144) {              // W -> Wf (rg32: Wq 0-31|Wk|Wv|Wo 96-127)
    int g = (bid - 4096) * 256 + t;
    int rg = g >> 12, kt = (g >> 6) & 63, lane = g & 63;
    const float* src = (rg < 32) ? Wq : (rg < 64) ? Wk : (rg < 96) ? Wv : Wo;
    int row = (rg & 31) * 32 + (lane & 31);
    int k = kt * 16 + (lane >> 5) * 8;
    const float* s = src + (size_t)row * 1024 + k;
    float4 v0 = *(const float4*)s;
    float4 v1 = *(const float4*)(s + 4);
    union { bf16_t b[8]; } pk;
    pk.b[0] = (bf16_t)v0.x; pk.b[1] = (bf16_t)v0.y; pk.b[2] = (bf16_t)v0.z; pk.b[3] = (bf16_t)v0.w;
    pk.b[4] = (bf16_t)v1.x; pk.b[5] = (bf16_t)v1.y; pk.b[6] = (bf16_t)v1.z; pk.b[7] = (bf16_t)v1.w;
    __builtin_memcpy(Wf + (size_t)g * 8, pk.b, 16);
  } else {                              // rope table
    int rb = bid - 6144;                // [0,128)
    int s = rb * 8 + (t >> 5);
    int f = t & 31;
    float p = (float)pos[s];
    float inv = powf(10000.0f, -(float)(2 * f) / 64.0f);
    float a = p * inv;
    rt[s * 32 + f] = make_float2(cosf(a), sinf(a));
  }
}

// ==== R18 GEMM body: 256x128 tile, 4 waves (2M x 2N), wave=128x64, 32x32 ====
// Per kt16 step: 4 A + 2 B fragment loads (6KB), 8 MFMA(32x32x16). 64 steps.
// P/Q double buffer. acc[4][2] f32x16 = 128 VGPR, frags 2x6x4 = 48.
#define GEMM_WIDE_BODY(AfBase, BfBase)                                         \
  const int t = threadIdx.x;                                                   \
  const int lane = t & 63, w = t >> 6;          /* w in [0,4) */               \
  const int c5 = lane & 31, h2 = lane >> 5;                                    \
  const int wm = w >> 1, wn = w & 1;                                           \
  const bf16_t* Ab = (AfBase) + (size_t)((i0 >> 5) + wm * 4) * 32768 + lane * 8; \
  const bf16_t* Bb = (BfBase) + (size_t)((e0 >> 5) + wn * 2) * 32768 + lane * 8; \
  bf16x8 pA[4], pB[2], qA[4], qB[2];                                           \
  f32x16 acc[4][2] = {};                                                       \
  auto loadP = [&](int kt) {                                                   \
    _Pragma("unroll") for (int f = 0; f < 4; ++f)                              \
      pA[f] = *(const bf16x8*)(Ab + (size_t)f * 32768 + kt * 512);             \
    _Pragma("unroll") for (int f = 0; f < 2; ++f)                              \
      pB[f] = *(const bf16x8*)(Bb + (size_t)f * 32768 + kt * 512);             \
  };                                                                           \
  auto loadQ = [&](int kt) {                                                   \
    _Pragma("unroll") for (int f = 0; f < 4; ++f)                              \
      qA[f] = *(const bf16x8*)(Ab + (size_t)f * 32768 + kt * 512);             \
    _Pragma("unroll") for (int f = 0; f < 2; ++f)                              \
      qB[f] = *(const bf16x8*)(Bb + (size_t)f * 32768 + kt * 512);             \
  };                                                                           \
  auto compP = [&]() {                                                         \
    __builtin_amdgcn_s_setprio(1);                                             \
    _Pragma("unroll") for (int fr = 0; fr < 4; ++fr)                           \
      _Pragma("unroll") for (int nc = 0; nc < 2; ++nc)                         \
        acc[fr][nc] = mfma32(pA[fr], pB[nc], acc[fr][nc]);                     \
    __builtin_amdgcn_s_setprio(0);                                             \
  };                                                                           \
  auto compQ = [&]() {                                                         \
    __builtin_amdgcn_s_setprio(1);                                             \
    _Pragma("unroll") for (int fr = 0; fr < 4; ++fr)                           \
      _Pragma("unroll") for (int nc = 0; nc < 2; ++nc)                         \
        acc[fr][nc] = mfma32(qA[fr], qB[nc], acc[fr][nc]);                     \
    __builtin_amdgcn_s_setprio(0);                                             \
  };                                                                           \
  loadP(0);                                                                    \
  loadQ(1);                                                                    \
  _Pragma("unroll 3")                                                          \
  for (int jj = 0; jj < 31; ++jj) {                                            \
    compP(); loadP(jj * 2 + 2);                                                \
    compQ(); loadQ(jj * 2 + 3);                                                \
  }                                                                            \
  compP();                                                                     \
  compQ();

// ---------------- fused QKV GEMM: N=3072, 768 blocks, XCD m-chunk ---------
// XCD x owns m [1024x,1024x+1024) = batch x; m-fastest within XCD. C/D map:
// lane (c5,h2), reg=4q+r -> row = fr*32 + 8q + 4h2 + r, col = nc*32 + c5.
__global__ __launch_bounds__(256) void k_gemm_qkv(
    const bf16_t* __restrict__ Xf, const bf16_t* __restrict__ Wf,
    const float* __restrict__ bq, const float* __restrict__ bk,
    const float* __restrict__ bv, const float2* __restrict__ rt,
    bf16_t* __restrict__ Qh, bf16_t* __restrict__ Kg, bf16_t* __restrict__ Vg) {
  const int bid = blockIdx.x;
  const int x = bid & 7, q = bid >> 3;           // q in [0,96)
  const int i0 = (x * 4 + (q & 3)) * 256;
  const int e0 = (q >> 2) * 128;

  GEMM_WIDE_BODY(Xf, Wf)

  const int z = e0 >> 10;                       // 0:Q 1:K 2:V
  const int ez0 = (e0 & 1023) + wn * 64;        // head base (64-wide)
  const int h = ez0 >> 6;
  const float* bias = (z == 0) ? bq : (z == 1) ? bk : bv;
  const int i0w = i0 + wm * 128;
  const int b_ = i0w >> 10, sl0 = i0w & 1023;

  if (z == 2) {
    // V -> V^T 16-granule (attn layout, unchanged): for dk = nc*32 + c5:
    // nc16 = dk>>4 = nc*2 + (c5>>4); lane16 = (dk&15)|(q<<4); elem = 4h2+r.
    const int bhv = b_ * 16 + h;
#pragma unroll
    for (int fr = 0; fr < 4; ++fr) {
#pragma unroll
      for (int nc = 0; nc < 2; ++nc) {
        float bv_ = bias[ez0 + nc * 32 + c5];
        size_t gbase = ((size_t)(bhv * 4 + nc * 2 + (c5 >> 4)) * 32 +
                        (sl0 >> 5) + fr) * 512;
#pragma unroll
        for (int q_ = 0; q_ < 4; ++q_) {
          union { bf16_t b[4]; } pk;
#pragma unroll
          for (int r = 0; r < 4; ++r) pk.b[r] = (bf16_t)(acc[fr][nc][4 * q_ + r] + bv_);
          __builtin_memcpy(&Vg[gbase + (size_t)((c5 & 15) | (q_ << 4)) * 8 + h2 * 4],
                           pk.b, 8);
        }
      }
    }
  } else if (z == 0) {
    // Q row-major with rope; folds 1/sqrt(64)*log2(e). f = c5, partner nc=1.
    const float scl = 0.18033688011112042f;
    const float b1_ = bias[ez0 + c5], b2_ = bias[ez0 + 32 + c5];
    size_t obase = (size_t)((b_ * 16 + h)) * 1024;
#pragma unroll
    for (int fr = 0; fr < 4; ++fr)
#pragma unroll
      for (int q_ = 0; q_ < 4; ++q_)
#pragma unroll
        for (int r = 0; r < 4; ++r) {
          int sl = sl0 + fr * 32 + 8 * q_ + 4 * h2 + r;
          float2 cs = rt[sl * 32 + c5];
          float q1 = acc[fr][0][4 * q_ + r] + b1_;
          float q2 = acc[fr][1][4 * q_ + r] + b2_;
          Qh[(obase + sl) * 64 + c5] = (bf16_t)((q1 * cs.x - q2 * cs.y) * scl);
          Qh[(obase + sl) * 64 + c5 + 32] = (bf16_t)((q1 * cs.y + q2 * cs.x) * scl);
        }
  } else {
    // K -> 16-granule with rope (attn layout, unchanged): dk = c5 / c5+32.
    const float b1_ = bias[ez0 + c5], b2_ = bias[ez0 + 32 + c5];
    bf16_t* gb0 = Kg + (size_t)((b_ * 16 + h) * 64) * 1024;
    const int lane16hi = ((c5 >> 3) & 3) << 4;
#pragma unroll
    for (int fr = 0; fr < 4; ++fr)
#pragma unroll
      for (int q_ = 0; q_ < 4; ++q_)
#pragma unroll
        for (int r = 0; r < 4; ++r) {
          int sl = sl0 + fr * 32 + 8 * q_ + 4 * h2 + r;
          float2 cs = rt[sl * 32 + c5];
          float q1 = acc[fr][0][4 * q_ + r] + b1_;
          float q2 = acc[fr][1][4 * q_ + r] + b2_;
          bf16_t* gbs = gb0 + (size_t)(sl >> 4) * 1024;
          size_t off = (size_t)((sl & 15) | lane16hi) * 8 + (c5 & 7);
          gbs[off] = (bf16_t)(q1 * cs.x - q2 * cs.y);
          gbs[off + 512] = (bf16_t)(q1 * cs.y + q2 * cs.x);
        }
  }
}

// ---------------- out projection: 256 blocks, same 32x32 engine -----------
__global__ __launch_bounds__(256) void k_gemm_out(
    const bf16_t* __restrict__ Ogf, const bf16_t* __restrict__ Wf,
    const float* __restrict__ bo, float* __restrict__ out) {
  const int bid = blockIdx.x;
  const int x = bid & 7, q = bid >> 3;           // q in [0,32)
  const int i0 = (x * 4 + (q & 3)) * 256;
  const int e0 = (q >> 2) * 128;
  const bf16_t* WfO = Wf + (size_t)96 * 32768;   // Wo rg32 groups 96..127

  GEMM_WIDE_BODY(Ogf, WfO)

  const int i0w = i0 + wm * 128;
#pragma unroll
  for (int fr = 0; fr < 4; ++fr)
#pragma unroll
    for (int nc = 0; nc < 2; ++nc) {
      int e = e0 + wn * 64 + nc * 32 + c5;
      float bv_ = bo[e];
#pragma unroll
      for (int q_ = 0; q_ < 4; ++q_)
#pragma unroll
        for (int r = 0; r < 4; ++r) {
          int i = i0w + fr * 32 + 8 * q_ + 4 * h2 + r;
          out[(size_t)i * 1024 + e] = acc[fr][nc][4 * q_ + r] + bv_;
        }
    }
}

// ---------------- flash attention (R16 compute + 32-granule epilogue) -----
__global__ __launch_bounds__(512) void k_attn(
    const bf16_t* __restrict__ Qh, const bf16_t* __restrict__ Kg,
    const bf16_t* __restrict__ Vg, bf16_t* __restrict__ Ogf) {
  __shared__ alignas(16) char PL[8][2048];
  const int t = threadIdx.x;
  const int lane = t & 63, w = t >> 6;
  const int hi = lane >> 4, c = lane & 15;
  const int bid = blockIdx.x;
  const int wg = (bid & 7) * 32 + (bid >> 3);    // XCD x -> bh [16x,16x+16)
  const int bh = wg >> 1, half = wg & 1;
  const int q0 = half * 512 + w * 64;
  const size_t qbase = (size_t)bh * 64 * 1024;

  const bf16_t* Kb = Kg + (size_t)bh * 65536 + lane * 8;
  const bf16_t* Vb = Vg + (size_t)bh * 65536 + lane * 8;

  bf16x8 qf[4][2];
#pragma unroll
  for (int ss = 0; ss < 4; ++ss)
#pragma unroll
    for (int kk = 0; kk < 2; ++kk)
      qf[ss][kk] = *(const bf16x8*)&Qh[qbase + (size_t)(q0 + ss * 16 + c) * 64 +
                                       kk * 32 + hi * 8];

  f32x4 o[4][4] = {};
  float m_[4] = {-1e30f, -1e30f, -1e30f, -1e30f};
  float l_[4] = {0.f, 0.f, 0.f, 0.f};
  char* const plw = &PL[w][0];

  bf16x8 kp[8], kq[8], vv[8];
#pragma unroll
  for (int i = 0; i < 8; ++i) kp[i] = *(const bf16x8*)(Kb + i * 512);

#define SM_PV(ST, M, L, O)                                                     \
  {                                                                            \
    float pmax = -1e30f;                                                       \
    _Pragma("unroll") for (int ni = 0; ni < 4; ++ni)                           \
      _Pragma("unroll") for (int r = 0; r < 4; ++r)                            \
        pmax = fmaxf(pmax, ST[ni][r]);                                         \
    pmax = fmaxf(pmax, __shfl_xor(pmax, 16));                                  \
    pmax = fmaxf(pmax, __shfl_xor(pmax, 32));                                  \
    if (!__all(pmax <= M + 8.0f)) {        /* T13 defer-max (THR=8) */         \
      float mn = fmaxf(M, pmax);                                               \
      float sc = EXP2F(M - mn);                                                \
      M = mn;                                                                  \
      L *= sc;                                                                 \
      _Pragma("unroll") for (int od = 0; od < 4; ++od)                         \
        _Pragma("unroll") for (int r = 0; r < 4; ++r) O[od][r] *= sc;          \
    }                                                                          \
    float psum = 0.f;                                                          \
    _Pragma("unroll") for (int ni = 0; ni < 4; ++ni) {                         \
      union { bf16_t b[4]; } pk;                                               \
      _Pragma("unroll") for (int r = 0; r < 4; ++r) {                          \
        float p = EXP2F(ST[ni][r] - M);                                        \
        psum += p;                                                             \
        pk.b[r] = (bf16_t)p;                                                   \
      }                                                                        \
      __builtin_memcpy(plw + (ni * 2 + (hi >> 1)) * 256 + c * 16 + (hi & 1) * 8, \
                       pk.b, 8);                                               \
    }                                                                          \
    psum += __shfl_xor(psum, 16);                                              \
    psum += __shfl_xor(psum, 32);                                              \
    L += psum;                                                                 \
    bf16x8 pa[2];                                                              \
    __builtin_memcpy(&pa[0], plw + lane * 16, 16);                             \
    __builtin_memcpy(&pa[1], plw + 1024 + lane * 16, 16);                      \
    _Pragma("unroll") for (int od = 0; od < 4; ++od)                           \
      _Pragma("unroll") for (int kk = 0; kk < 2; ++kk)                         \
        O[od] = mfma16(vv[od * 2 + kk], pa[kk], O[od]);                        \
  }

#define ATTN_TILE(KS, KN, KT)                                                  \
  {                                                                            \
    _Pragma("unroll") for (int i = 0; i < 8; ++i)                              \
      vv[i] = *(const bf16x8*)(Vb + ((i >> 1) * 32 + (KT) * 2 + (i & 1)) * 512); \
    _Pragma("unroll") for (int ss = 0; ss < 4; ++ss) {                         \
      f32x4 st[4] = {};                                                        \
      _Pragma("unroll") for (int ni = 0; ni < 4; ++ni)                         \
        _Pragma("unroll") for (int kk = 0; kk < 2; ++kk)                       \
          st[ni] = mfma16(KS[ni * 2 + kk], qf[ss][kk], st[ni]);                \
      if (ss == 0 && (KT) + 1 < 16) {                                          \
        _Pragma("unroll") for (int i = 0; i < 8; ++i)                          \
          KN[i] = *(const bf16x8*)(Kb + (((KT) + 1) * 8 + i) * 512);           \
      }                                                                        \
      SM_PV(st, m_[ss], l_[ss], o[ss])                                         \
    }                                                                          \
  }

  for (int jj = 0; jj < 8; ++jj) {
    ATTN_TILE(kp, kq, jj * 2);
    ATTN_TILE(kq, kp, jj * 2 + 1);
  }
#undef ATTN_TILE
#undef SM_PV

  // Epilogue -> Ogf 32-granule. Out element: row = b*1024 + q0 + ss*16 + c,
  // col = h*64 + od*16 + hi*4 + r. rg32 = row>>5; l32 = (row&31)|((hi>>1)<<5);
  // kt16 = h*4 + od; j0 = (hi&1)*4.
  int b_ = bh >> 4, h = bh & 15;
  int rgb = ((b_ << 10) + q0) >> 5;
#pragma unroll
  for (int ss = 0; ss < 4; ++ss) {
    float iv = 1.f / l_[ss];
    int rg32 = rgb + (ss >> 1);
    int l32 = ((ss & 1) * 16 + c) | ((hi >> 1) << 5);
#pragma unroll
    for (int od = 0; od < 4; ++od) {
      union { bf16_t b[4]; } pk;
#pragma unroll
      for (int r = 0; r < 4; ++r) pk.b[r] = (bf16_t)(o[ss][od][r] * iv);
      int kt16 = h * 4 + od;
      __builtin_memcpy(&Ogf[((size_t)(rg32 * 64 + kt16) * 64 + l32) * 8 + (hi & 1) * 4],
                       pk.b, 8);
    }
  }
}

extern "C" void kernel_launch(void* const* d_in, const int* in_sizes, int n_in,
                              void* d_out, int out_size, void* d_ws, size_t ws_size,
                              hipStream_t stream) {
  const float* x = (const float*)d_in[0];
  const int* pos = (const int*)d_in[1];
  const float* Wq = (const float*)d_in[2];
  const float* bq = (const float*)d_in[3];
  const float* Wk = (const float*)d_in[4];
  const float* bk = (const float*)d_in[5];
  const float* Wv = (const float*)d_in[6];
  const float* bv = (const float*)d_in[7];
  const float* Wo = (const float*)d_in[8];
  const float* bo = (const float*)d_in[9];
  float* out = (float*)d_out;

  // ws: [0,16M) Xf (32-granule; reused as Ogf) | [16M,24M) Wf (32-granule)
  //     [24M,40M) Vg (V^T 16-granule) | [42M,..) rope table.
  // Qh (row-major) + Kg (16-granule) live in d_out (16MB each).
  char* ws = (char*)d_ws;
  bf16_t* Xf = (bf16_t*)ws;
  bf16_t* Wf = (bf16_t*)(ws + (16u << 20));
  bf16_t* Vg = (bf16_t*)(ws + (24u << 20));
  float2* rt = (float2*)(ws + (42u << 20));
  bf16_t* Qh = (bf16_t*)d_out;
  bf16_t* Kg = (bf16_t*)d_out + (size_t)8 * 1024 * 1024;
  bf16_t* Ogf = Xf;

  k_prep<<<6272, 256, 0, stream>>>(x, Wq, Wk, Wv, Wo, pos, Xf, Wf, rt);
  k_gemm_qkv<<<768, 256, 0, stream>>>(Xf, Wf, bq, bk, bv, rt, Qh, Kg, Vg);
  k_attn<<<256, 512, 0, stream>>>(Qh, Kg, Vg, Ogf);
  k_gemm_out<<<256, 256, 0, stream>>>(Ogf, Wf, bo, out);
}